// Round 13
// baseline (233.400 us; speedup 1.0000x reference)
//
#include <hip/hip_runtime.h>
#include <hip/hip_bf16.h>

#define EMBED 256
#define HEADS 8
#define BATCH 8
#define SEQ   1024
#define NROWS 8192

typedef __attribute__((ext_vector_type(8))) _Float16 half8;   // 8 fp16
typedef __attribute__((ext_vector_type(4))) float f32x4;
typedef unsigned int  uint;
typedef unsigned short ushort;

#define QE   ((size_t)2097152)   /* per-head elems: 8192*256 */

__device__ __forceinline__ ushort f2h(float f) {
    union { _Float16 h; ushort u; } cv; cv.h = (_Float16)f; return cv.u;
}

// ---------------------------------------------------------------------------
// K0: fp32 -> fp16 convert for X and all weights, one launch.
// ---------------------------------------------------------------------------
__global__ __launch_bounds__(256) void convert_f16(
    const float* __restrict__ X,  const float* __restrict__ Wq,
    const float* __restrict__ Wk, const float* __restrict__ Wv,
    const float* __restrict__ Wo,
    ushort* __restrict__ Xf, ushort* __restrict__ Wqkf,
    ushort* __restrict__ Wvf, ushort* __restrict__ Wof)
{
    const int blk = blockIdx.x;
    const float* src; ushort* dst; int i;
    if (blk < 2048)      { src = X;  dst = Xf;            i = blk * 256 + threadIdx.x; }
    else if (blk < 2560) { src = Wq; dst = Wqkf;          i = (blk - 2048) * 256 + threadIdx.x; }
    else if (blk < 3072) { src = Wk; dst = Wqkf + 524288; i = (blk - 2560) * 256 + threadIdx.x; }
    else if (blk < 3584) { src = Wv; dst = Wvf;           i = (blk - 3072) * 256 + threadIdx.x; }
    else                 { src = Wo; dst = Wof;           i = (blk - 3584) * 256 + threadIdx.x; }
    const float4 v = ((const float4*)src)[i];
    uint2 P;
    P.x = (uint)f2h(v.x) | ((uint)f2h(v.y) << 16);
    P.y = (uint)f2h(v.z) | ((uint)f2h(v.w) << 16);
    ((uint2*)dst)[i] = P;
}

// ---------------------------------------------------------------------------
// Single-pass fp16 MFMA GEMM core (NT): BM=BN=128, BK=64, KD=256,
// 256 threads = 4 waves (2x2). mode 0: q/k write; mode 1: vt write.
// ---------------------------------------------------------------------------
__device__ __forceinline__ void gemm1p_core(
    const ushort* __restrict__ Ag, const ushort* __restrict__ Bg,
    ushort* __restrict__ o0, ushort* __restrict__ o1,
    ushort* Ah, ushort* Bh, int m0, int n0, int mode)
{
    const int tid = threadIdx.x, w = tid >> 6, l = tid & 63;
    const int wr = w >> 1, wc = w & 1, g = l >> 4, c16 = l & 15;
    const int sr = l >> 3, sb = l & 7;

    f32x4 acc[4][4];
#pragma unroll
    for (int mi = 0; mi < 4; ++mi)
#pragma unroll
        for (int ni = 0; ni < 4; ++ni) acc[mi][ni] = (f32x4){0.f, 0.f, 0.f, 0.f};

    for (int k0 = 0; k0 < 256; k0 += 64) {
        __syncthreads();
#pragma unroll
        for (int j = 0; j < 4; ++j) {
            const int rb = w * 32 + j * 8;
            const int r  = rb + sr;
            const size_t srcA = (size_t)(m0 + r) * 256 + k0 + ((sb ^ (r & 7)) * 8);
            __builtin_amdgcn_global_load_lds(Ag + srcA, &Ah[rb * 64], 16, 0, 0);
            const size_t srcB = (size_t)(n0 + r) * 256 + k0 + ((sb ^ (r & 7)) * 8);
            __builtin_amdgcn_global_load_lds(Bg + srcB, &Bh[rb * 64], 16, 0, 0);
        }
        asm volatile("s_waitcnt vmcnt(0)" ::: "memory");
        __syncthreads();

#pragma unroll
        for (int kh = 0; kh < 2; ++kh) {
            const int bsel = ((kh << 2) | g) ^ (c16 & 7);
            half8 af[4], bf[4];
#pragma unroll
            for (int mi = 0; mi < 4; ++mi)
                af[mi] = *(const half8*)&Ah[(wr * 64 + mi * 16 + c16) * 64 + bsel * 8];
#pragma unroll
            for (int ni = 0; ni < 4; ++ni)
                bf[ni] = *(const half8*)&Bh[(wc * 64 + ni * 16 + c16) * 64 + bsel * 8];
#pragma unroll
            for (int mi = 0; mi < 4; ++mi)
#pragma unroll
                for (int ni = 0; ni < 4; ++ni)
                    acc[mi][ni] = __builtin_amdgcn_mfma_f32_16x16x32_f16(af[mi], bf[ni], acc[mi][ni], 0, 0, 0);
        }
    }

#pragma unroll
    for (int mi = 0; mi < 4; ++mi)
#pragma unroll
        for (int ni = 0; ni < 4; ++ni) {
            const int n = n0 + wc * 64 + ni * 16 + c16;
            if (mode == 0) {
                const int op = n >> 11, hh = (n >> 8) & 7, d = n & 255;
                ushort* tq = (op ? o1 : o0) + (size_t)hh * QE + d;
#pragma unroll
                for (int j = 0; j < 4; ++j) {
                    const int m = m0 + wr * 64 + mi * 16 + 4 * g + j;
                    tq[(size_t)m * 256] = f2h(acc[mi][ni][j]);
                }
            } else {
#pragma unroll
                for (int j = 0; j < 4; ++j) {
                    const int m = m0 + wr * 64 + mi * 16 + 4 * g + j;
                    o0[(size_t)m * NROWS + n] = f2h(acc[mi][ni][j]);
                }
            }
        }
}

// Merged QK + VT projection launch: bid<2048 -> qk GEMM, else vt GEMM.
// vt part: n is the XCD-partitioned dim (8 n-tiles/XCD -> X footprint 512KB
// + Wv 1MB per XCD, fits 4MB L2; was m-partitioned -> X 4MB thrash).
__global__ __launch_bounds__(256) void gemm_qkvt(
    const ushort* __restrict__ Xf,
    const ushort* __restrict__ Wqkf, const ushort* __restrict__ Wvf,
    ushort* __restrict__ qf, ushort* __restrict__ kf, ushort* __restrict__ vtb)
{
    __shared__ __align__(16) ushort Ah[128 * 64];
    __shared__ __align__(16) ushort Bh[128 * 64];
    const int bid = blockIdx.x;
    if (bid < 2048) {
        const int wg = (bid & 7) * 256 + (bid >> 3);
        gemm1p_core(Xf, Wqkf, qf, kf, Ah, Bh, (wg >> 5) * 128, (wg & 31) * 128, 0);
    } else {
        const int b2 = bid - 2048;
        const int wg = (b2 & 7) * 128 + (b2 >> 3);
        gemm1p_core(Wvf, Xf, vtb, nullptr, Ah, Bh, (wg & 15) * 128, (wg >> 4) * 128, 1);
    }
}

// ---------------------------------------------------------------------------
// K3: fp16 output projection, BM=64 x BN=64 -> 512 blocks. LDS 16KB.
// ---------------------------------------------------------------------------
__global__ __launch_bounds__(256) void gemm_out_f16(
    const ushort* __restrict__ A, const ushort* __restrict__ Bw,
    const float* __restrict__ bias, float* __restrict__ fo)
{
    __shared__ __align__(16) ushort Ah[64 * 64];
    __shared__ __align__(16) ushort Bh[64 * 64];

    const int wg = (blockIdx.x & 7) * 64 + (blockIdx.x >> 3);
    const int m0 = (wg >> 2) * 64;
    const int n0 = (wg & 3) * 64;

    const int tid = threadIdx.x, w = tid >> 6, l = tid & 63;
    const int wr = w >> 1, wc = w & 1, g = l >> 4, c16 = l & 15;
    const int sr = l >> 3, sb = l & 7;

    f32x4 acc[2][2];
#pragma unroll
    for (int mi = 0; mi < 2; ++mi)
#pragma unroll
        for (int ni = 0; ni < 2; ++ni) acc[mi][ni] = (f32x4){0.f, 0.f, 0.f, 0.f};

    for (int k0 = 0; k0 < 2048; k0 += 64) {
        __syncthreads();
#pragma unroll
        for (int j = 0; j < 2; ++j) {
            const int rb = w * 16 + j * 8;
            const int r  = rb + sr;
            const size_t srcA = (size_t)(m0 + r) * 2048 + k0 + ((sb ^ (r & 7)) * 8);
            __builtin_amdgcn_global_load_lds(A + srcA, &Ah[rb * 64], 16, 0, 0);
            const size_t srcB = (size_t)(n0 + r) * 2048 + k0 + ((sb ^ (r & 7)) * 8);
            __builtin_amdgcn_global_load_lds(Bw + srcB, &Bh[rb * 64], 16, 0, 0);
        }
        asm volatile("s_waitcnt vmcnt(0)" ::: "memory");
        __syncthreads();

#pragma unroll
        for (int kh = 0; kh < 2; ++kh) {
            const int bsel = ((kh << 2) | g) ^ (c16 & 7);
            half8 af[2], bf[2];
#pragma unroll
            for (int mi = 0; mi < 2; ++mi)
                af[mi] = *(const half8*)&Ah[(wr * 32 + mi * 16 + c16) * 64 + bsel * 8];
#pragma unroll
            for (int ni = 0; ni < 2; ++ni)
                bf[ni] = *(const half8*)&Bh[(wc * 32 + ni * 16 + c16) * 64 + bsel * 8];
#pragma unroll
            for (int mi = 0; mi < 2; ++mi)
#pragma unroll
                for (int ni = 0; ni < 2; ++ni)
                    acc[mi][ni] = __builtin_amdgcn_mfma_f32_16x16x32_f16(af[mi], bf[ni], acc[mi][ni], 0, 0, 0);
        }
    }

#pragma unroll
    for (int mi = 0; mi < 2; ++mi)
#pragma unroll
        for (int ni = 0; ni < 2; ++ni) {
            const int n = n0 + wc * 32 + ni * 16 + c16;
            const float bb = bias[n];
#pragma unroll
            for (int j = 0; j < 4; ++j) {
                const int m = m0 + wr * 32 + mi * 16 + 4 * g + j;
                fo[(size_t)m * 256 + n] = acc[mi][ni][j] + bb;
            }
        }
}

// ---------------------------------------------------------------------------
// K2: fp16 MFMA flash attention — 8-wave (512-thread) blocks.
// 512 blocks = 64 hb x 8 qst (128 q-rows/block, 16 q/wave), all co-resident
// (2 blocks/CU x 8 waves = 16 waves/CU). LDS 56KB: K dbuf 32K + VT 16K + P 8K.
// Staging amortized over 8 waves: 2 gload_lds K + 2 VT per wave per ktile.
// Counted vmcnt: barrier1 waits vmcnt(2) (own VT; K[kt+1] in flight),
// barrier2 vmcnt(0). qst pairing (bid, bid+256) -> complementary work.
// ---------------------------------------------------------------------------
__global__ __launch_bounds__(512, 4) void flash_mfma(
    const ushort* __restrict__ qf, const ushort* __restrict__ kf,
    const ushort* __restrict__ vt, ushort* __restrict__ ocf)
{
    __shared__ __align__(16) ushort Ks[2][32 * 256];
    __shared__ __align__(16) ushort VTs[256 * 32];
    __shared__ __align__(16) ushort Pls[8][512];

    const int bid = blockIdx.x;
    const int hb  = (bid & 7) * 8 + ((bid >> 3) & 7);   // same-XCD hb groups
    const int i2  = bid >> 6;                           // 0..7
    const int qst = (i2 < 4) ? (7 - 2 * i2) : (2 * i2 - 8);  // pair-balanced
    const int h = hb >> 3, b = hb & 7;

    const int tid = threadIdx.x;
    const int w = tid >> 6, l = tid & 63;
    const int g = l >> 4, c16 = l & 15;
    const size_t qk_base = (size_t)h * QE + (size_t)b * (SEQ * EMBED);
    const size_t vt_base = (size_t)h * QE + (size_t)b * SEQ;

    const int psw = (c16 >> 1) & 3;
    const int rsw = c16 & 7;
    const int qw0 = qst * 128 + w * 16;
    const int q0 = qw0 + c16;

    half8 qfr[8];
    {
        const ushort* qr = qf + qk_base + (size_t)q0 * EMBED + g * 8;
#pragma unroll
        for (int kc = 0; kc < 8; ++kc)
            qfr[kc] = *(const half8*)(qr + kc * 32);
    }

    const ushort* kbase = kf + qk_base;
    const ushort* vbase = vt + vt_base;
    const int krow_l = l >> 5, kblk = l & 31;
    const int vd_l = l >> 2,  vblk = l & 3;
    uint koff[2], voff[2];
#pragma unroll
    for (int j = 0; j < 2; ++j) {
        const int row = 4 * w + 2 * j + krow_l;
        koff[j] = (uint)(row * EMBED + ((kblk ^ (row & 7)) * 8));
        const int d = w * 32 + j * 16 + vd_l;
        const int phi = ((d >> 1) ^ (d >> 3)) & 3;
        voff[j] = (uint)(d * NROWS + ((vblk ^ phi) * 8));
    }

    f32x4 acc[16];
#pragma unroll
    for (int dt = 0; dt < 16; ++dt) acc[dt] = (f32x4){0.f, 0.f, 0.f, 0.f};
    float m_r = -1e30f, l_p = 0.f;

    char* pw = (char*)&Pls[w][0];
    const int nkt = 4 * qst + 4;

    // prologue: stage K[0]
#pragma unroll
    for (int j = 0; j < 2; ++j)
        __builtin_amdgcn_global_load_lds(kbase + koff[j], &Ks[0][(4 * w + 2 * j) * 256], 16, 0, 0);
    asm volatile("s_waitcnt vmcnt(0)" ::: "memory");
    __builtin_amdgcn_s_barrier();
    __builtin_amdgcn_sched_barrier(0);

    for (int kt = 0; kt < nkt; ++kt) {
        // issue VT[kt] FIRST (oldest -> covered by vmcnt(2)), then K[kt+1].
#pragma unroll
        for (int j = 0; j < 2; ++j)
            __builtin_amdgcn_global_load_lds(vbase + voff[j] + kt * 32,
                                             &VTs[(w * 32 + j * 16) * 32], 16, 0, 0);
        const bool havek = (kt + 1 < nkt);
        if (havek) {
            const ushort* kb = kbase + (size_t)(kt + 1) * (32 * EMBED);
#pragma unroll
            for (int j = 0; j < 2; ++j)
                __builtin_amdgcn_global_load_lds(kb + koff[j],
                                                 &Ks[(kt + 1) & 1][(4 * w + 2 * j) * 256], 16, 0, 0);
        }

        const bool active = (kt * 32 <= qw0 + 15);
        if (active) {
            // ---- QK^T on K[kt] (complete since previous barrier2) ----
            const ushort* Kb = &Ks[kt & 1][0];
            f32x4 s0 = (f32x4){0.f, 0.f, 0.f, 0.f};
            f32x4 s1 = (f32x4){0.f, 0.f, 0.f, 0.f};
#pragma unroll
            for (int kc = 0; kc < 8; ++kc) {
                const int blk = ((kc * 4 + g) ^ rsw) * 8;
                const half8 a0 = *(const half8*)&Kb[c16 * 256 + blk];
                const half8 a1 = *(const half8*)&Kb[(c16 + 16) * 256 + blk];
                s0 = __builtin_amdgcn_mfma_f32_16x16x32_f16(a0, qfr[kc], s0, 0, 0, 0);
                s1 = __builtin_amdgcn_mfma_f32_16x16x32_f16(a1, qfr[kc], s1, 0, 0, 0);
            }
            const int k0b = kt * 32 + 4 * g;
            float p0[4], p1[4];
            float pm = -1e30f;
#pragma unroll
            for (int r = 0; r < 4; ++r) {
                p0[r] = (k0b + r      > q0) ? -1e30f : s0[r];
                p1[r] = (k0b + 16 + r > q0) ? -1e30f : s1[r];
                pm = fmaxf(pm, fmaxf(p0[r], p1[r]));
            }
            if (__any(pm > m_r + 8.f)) {
                float gm = fmaxf(pm, __shfl_xor(pm, 16));
                gm = fmaxf(gm, __shfl_xor(gm, 32));
                const float mn = fmaxf(m_r, gm);
                const float sc = __expf(m_r - mn);
                l_p *= sc;
#pragma unroll
                for (int dt = 0; dt < 16; ++dt) acc[dt] *= sc;
                m_r = mn;
            }
#pragma unroll
            for (int r = 0; r < 4; ++r) {
                p0[r] = __expf(p0[r] - m_r);
                p1[r] = __expf(p1[r] - m_r);
                l_p += p0[r] + p1[r];
            }
#pragma unroll
            for (int t = 0; t < 2; ++t)
#pragma unroll
                for (int u = 0; u < 2; ++u) {
                    const int kk = 16 * t + 4 * g + 2 * u;
                    const int off = c16 * 64 + (((kk >> 3) ^ psw) * 16) + (kk & 7) * 2;
                    const float lo = t ? p1[2 * u] : p0[2 * u];
                    const float hi = t ? p1[2 * u + 1] : p0[2 * u + 1];
                    *(uint*)(pw + off) = (uint)f2h(lo) | ((uint)f2h(hi) << 16);
                }
        }

        // barrier1: own VT landed (K[kt+1] stays in flight when havek)
        if (havek) asm volatile("s_waitcnt vmcnt(2)" ::: "memory");
        else       asm volatile("s_waitcnt vmcnt(0)" ::: "memory");
        __builtin_amdgcn_s_barrier();
        __builtin_amdgcn_sched_barrier(0);

        if (active) {
            const half8 pfrag = *(const half8*)(pw + c16 * 64 + ((g ^ psw) * 16));
#pragma unroll
            for (int dt = 0; dt < 16; ++dt) {
                const int d = dt * 16 + c16;
                const int phi = ((d >> 1) ^ (d >> 3)) & 3;
                const half8 va = *(const half8*)&VTs[d * 32 + ((g ^ phi) * 8)];
                acc[dt] = __builtin_amdgcn_mfma_f32_16x16x32_f16(va, pfrag, acc[dt], 0, 0, 0);
            }
        }

        // barrier2: own K[kt+1] landed; VT buffer free for next iter
        asm volatile("s_waitcnt vmcnt(0)" ::: "memory");
        __builtin_amdgcn_s_barrier();
        __builtin_amdgcn_sched_barrier(0);
    }

    l_p += __shfl_xor(l_p, 16);
    l_p += __shfl_xor(l_p, 32);
    const float inv = 1.f / l_p;
    ushort* orow = ocf + ((size_t)(b * SEQ) + q0) * (HEADS * EMBED) + h * EMBED;
#pragma unroll
    for (int dt = 0; dt < 16; ++dt) {
        const f32x4 o = acc[dt] * inv;
        uint2 P2;
        P2.x = (uint)f2h(o[0]) | ((uint)f2h(o[1]) << 16);
        P2.y = (uint)f2h(o[2]) | ((uint)f2h(o[3]) << 16);
        *(uint2*)(orow + dt * 16 + 4 * g) = P2;
    }
}

extern "C" void kernel_launch(void* const* d_in, const int* in_sizes, int n_in,
                              void* d_out, int out_size, void* d_ws, size_t ws_size,
                              hipStream_t stream) {
    const float* X  = (const float*)d_in[0];
    const float* Wq = (const float*)d_in[1];
    const float* Wk = (const float*)d_in[2];
    const float* Wv = (const float*)d_in[3];
    const float* Wo = (const float*)d_in[4];
    const float* bo = (const float*)d_in[5];

    ushort* ws16 = (ushort*)d_ws;
    ushort* qf   = ws16;                     // [8][8192][256] fp16
    ushort* kf   = ws16 +  8 * QE;           // fp16
    ushort* vtb  = ws16 + 16 * QE;           // [8][256][8192] fp16
    ushort* ocf  = ws16 + 24 * QE;           // [8192][2048] fp16
    ushort* ex   = ws16 + 32 * QE;
    ushort* Xf   = ex;                       // 2M fp16
    ushort* Wqkf = ex + 2097152;             // [4096][256] fp16
    ushort* Wvf  = ex + 2097152 + 1048576;   // [2048][256] fp16
    ushort* Wof  = ex + 2097152 + 1048576 + 524288;   // [256][2048] fp16
    float*  out  = (float*)d_out;

    convert_f16<<<4096, 256, 0, stream>>>(X, Wq, Wk, Wv, Wo, Xf, Wqkf, Wvf, Wof);

    gemm_qkvt<<<3072, 256, 0, stream>>>(Xf, Wqkf, Wvf, qf, kf, vtb);

    flash_mfma<<<512, 512, 0, stream>>>(qf, kf, vtb, ocf);

    gemm_out_f16<<<512, 256, 0, stream>>>(ocf, Wof, bo, out);
}

// Round 14
// 133.737 us; speedup vs baseline: 1.7452x; 1.7452x over previous
//
#include <hip/hip_runtime.h>
#include <hip/hip_bf16.h>

#define EMBED 256
#define HEADS 8
#define BATCH 8
#define SEQ   1024
#define NROWS 8192

typedef __attribute__((ext_vector_type(8))) _Float16 half8;   // 8 fp16
typedef __attribute__((ext_vector_type(4))) float f32x4;
typedef unsigned int  uint;
typedef unsigned short ushort;

#define QE   ((size_t)2097152)   /* per-head elems: 8192*256 */

__device__ __forceinline__ ushort f2h(float f) {
    union { _Float16 h; ushort u; } cv; cv.h = (_Float16)f; return cv.u;
}

// ---------------------------------------------------------------------------
// K0: fp32 -> fp16 convert for X and all weights, one launch.
// ---------------------------------------------------------------------------
__global__ __launch_bounds__(256) void convert_f16(
    const float* __restrict__ X,  const float* __restrict__ Wq,
    const float* __restrict__ Wk, const float* __restrict__ Wv,
    const float* __restrict__ Wo,
    ushort* __restrict__ Xf, ushort* __restrict__ Wqkf,
    ushort* __restrict__ Wvf, ushort* __restrict__ Wof)
{
    const int blk = blockIdx.x;
    const float* src; ushort* dst; int i;
    if (blk < 2048)      { src = X;  dst = Xf;            i = blk * 256 + threadIdx.x; }
    else if (blk < 2560) { src = Wq; dst = Wqkf;          i = (blk - 2048) * 256 + threadIdx.x; }
    else if (blk < 3072) { src = Wk; dst = Wqkf + 524288; i = (blk - 2560) * 256 + threadIdx.x; }
    else if (blk < 3584) { src = Wv; dst = Wvf;           i = (blk - 3072) * 256 + threadIdx.x; }
    else                 { src = Wo; dst = Wof;           i = (blk - 3584) * 256 + threadIdx.x; }
    const float4 v = ((const float4*)src)[i];
    uint2 P;
    P.x = (uint)f2h(v.x) | ((uint)f2h(v.y) << 16);
    P.y = (uint)f2h(v.z) | ((uint)f2h(v.w) << 16);
    ((uint2*)dst)[i] = P;
}

// ---------------------------------------------------------------------------
// Single-pass fp16 MFMA GEMM core (NT): BM=BN=128, BK=64, KD=256,
// 256 threads = 4 waves (2x2). mode 0: q/k write; mode 1: vt write.
// ---------------------------------------------------------------------------
__device__ __forceinline__ void gemm1p_core(
    const ushort* __restrict__ Ag, const ushort* __restrict__ Bg,
    ushort* __restrict__ o0, ushort* __restrict__ o1,
    ushort* Ah, ushort* Bh, int m0, int n0, int mode)
{
    const int tid = threadIdx.x, w = tid >> 6, l = tid & 63;
    const int wr = w >> 1, wc = w & 1, g = l >> 4, c16 = l & 15;
    const int sr = l >> 3, sb = l & 7;

    f32x4 acc[4][4];
#pragma unroll
    for (int mi = 0; mi < 4; ++mi)
#pragma unroll
        for (int ni = 0; ni < 4; ++ni) acc[mi][ni] = (f32x4){0.f, 0.f, 0.f, 0.f};

    for (int k0 = 0; k0 < 256; k0 += 64) {
        __syncthreads();
#pragma unroll
        for (int j = 0; j < 4; ++j) {
            const int rb = w * 32 + j * 8;
            const int r  = rb + sr;
            const size_t srcA = (size_t)(m0 + r) * 256 + k0 + ((sb ^ (r & 7)) * 8);
            __builtin_amdgcn_global_load_lds(Ag + srcA, &Ah[rb * 64], 16, 0, 0);
            const size_t srcB = (size_t)(n0 + r) * 256 + k0 + ((sb ^ (r & 7)) * 8);
            __builtin_amdgcn_global_load_lds(Bg + srcB, &Bh[rb * 64], 16, 0, 0);
        }
        asm volatile("s_waitcnt vmcnt(0)" ::: "memory");
        __syncthreads();

#pragma unroll
        for (int kh = 0; kh < 2; ++kh) {
            const int bsel = ((kh << 2) | g) ^ (c16 & 7);
            half8 af[4], bf[4];
#pragma unroll
            for (int mi = 0; mi < 4; ++mi)
                af[mi] = *(const half8*)&Ah[(wr * 64 + mi * 16 + c16) * 64 + bsel * 8];
#pragma unroll
            for (int ni = 0; ni < 4; ++ni)
                bf[ni] = *(const half8*)&Bh[(wc * 64 + ni * 16 + c16) * 64 + bsel * 8];
#pragma unroll
            for (int mi = 0; mi < 4; ++mi)
#pragma unroll
                for (int ni = 0; ni < 4; ++ni)
                    acc[mi][ni] = __builtin_amdgcn_mfma_f32_16x16x32_f16(af[mi], bf[ni], acc[mi][ni], 0, 0, 0);
        }
    }

#pragma unroll
    for (int mi = 0; mi < 4; ++mi)
#pragma unroll
        for (int ni = 0; ni < 4; ++ni) {
            const int n = n0 + wc * 64 + ni * 16 + c16;
            if (mode == 0) {
                const int op = n >> 11, hh = (n >> 8) & 7, d = n & 255;
                ushort* tq = (op ? o1 : o0) + (size_t)hh * QE + d;
#pragma unroll
                for (int j = 0; j < 4; ++j) {
                    const int m = m0 + wr * 64 + mi * 16 + 4 * g + j;
                    tq[(size_t)m * 256] = f2h(acc[mi][ni][j]);
                }
            } else {
#pragma unroll
                for (int j = 0; j < 4; ++j) {
                    const int m = m0 + wr * 64 + mi * 16 + 4 * g + j;
                    o0[(size_t)m * NROWS + n] = f2h(acc[mi][ni][j]);
                }
            }
        }
}

// Merged QK + VT projection launch: bid<2048 -> qk GEMM, else vt GEMM.
// vt part: n is the XCD-partitioned dim (X footprint 512KB + Wv 1MB per XCD).
__global__ __launch_bounds__(256) void gemm_qkvt(
    const ushort* __restrict__ Xf,
    const ushort* __restrict__ Wqkf, const ushort* __restrict__ Wvf,
    ushort* __restrict__ qf, ushort* __restrict__ kf, ushort* __restrict__ vtb)
{
    __shared__ __align__(16) ushort Ah[128 * 64];
    __shared__ __align__(16) ushort Bh[128 * 64];
    const int bid = blockIdx.x;
    if (bid < 2048) {
        const int wg = (bid & 7) * 256 + (bid >> 3);
        gemm1p_core(Xf, Wqkf, qf, kf, Ah, Bh, (wg >> 5) * 128, (wg & 31) * 128, 0);
    } else {
        const int b2 = bid - 2048;
        const int wg = (b2 & 7) * 128 + (b2 >> 3);
        gemm1p_core(Wvf, Xf, vtb, nullptr, Ah, Bh, (wg & 15) * 128, (wg >> 4) * 128, 1);
    }
}

// ---------------------------------------------------------------------------
// K3: fp16 output projection, BM=64 x BN=64 -> 512 blocks. LDS 16KB.
// ---------------------------------------------------------------------------
__global__ __launch_bounds__(256) void gemm_out_f16(
    const ushort* __restrict__ A, const ushort* __restrict__ Bw,
    const float* __restrict__ bias, float* __restrict__ fo)
{
    __shared__ __align__(16) ushort Ah[64 * 64];
    __shared__ __align__(16) ushort Bh[64 * 64];

    const int wg = (blockIdx.x & 7) * 64 + (blockIdx.x >> 3);
    const int m0 = (wg >> 2) * 64;
    const int n0 = (wg & 3) * 64;

    const int tid = threadIdx.x, w = tid >> 6, l = tid & 63;
    const int wr = w >> 1, wc = w & 1, g = l >> 4, c16 = l & 15;
    const int sr = l >> 3, sb = l & 7;

    f32x4 acc[2][2];
#pragma unroll
    for (int mi = 0; mi < 2; ++mi)
#pragma unroll
        for (int ni = 0; ni < 2; ++ni) acc[mi][ni] = (f32x4){0.f, 0.f, 0.f, 0.f};

    for (int k0 = 0; k0 < 2048; k0 += 64) {
        __syncthreads();
#pragma unroll
        for (int j = 0; j < 2; ++j) {
            const int rb = w * 16 + j * 8;
            const int r  = rb + sr;
            const size_t srcA = (size_t)(m0 + r) * 2048 + k0 + ((sb ^ (r & 7)) * 8);
            __builtin_amdgcn_global_load_lds(A + srcA, &Ah[rb * 64], 16, 0, 0);
            const size_t srcB = (size_t)(n0 + r) * 2048 + k0 + ((sb ^ (r & 7)) * 8);
            __builtin_amdgcn_global_load_lds(Bw + srcB, &Bh[rb * 64], 16, 0, 0);
        }
        asm volatile("s_waitcnt vmcnt(0)" ::: "memory");
        __syncthreads();

#pragma unroll
        for (int kh = 0; kh < 2; ++kh) {
            const int bsel = ((kh << 2) | g) ^ (c16 & 7);
            half8 af[2], bf[2];
#pragma unroll
            for (int mi = 0; mi < 2; ++mi)
                af[mi] = *(const half8*)&Ah[(wr * 32 + mi * 16 + c16) * 64 + bsel * 8];
#pragma unroll
            for (int ni = 0; ni < 2; ++ni)
                bf[ni] = *(const half8*)&Bh[(wc * 32 + ni * 16 + c16) * 64 + bsel * 8];
#pragma unroll
            for (int mi = 0; mi < 2; ++mi)
#pragma unroll
                for (int ni = 0; ni < 2; ++ni)
                    acc[mi][ni] = __builtin_amdgcn_mfma_f32_16x16x32_f16(af[mi], bf[ni], acc[mi][ni], 0, 0, 0);
        }
    }

#pragma unroll
    for (int mi = 0; mi < 2; ++mi)
#pragma unroll
        for (int ni = 0; ni < 2; ++ni) {
            const int n = n0 + wc * 32 + ni * 16 + c16;
            const float bb = bias[n];
#pragma unroll
            for (int j = 0; j < 4; ++j) {
                const int m = m0 + wr * 32 + mi * 16 + 4 * g + j;
                fo[(size_t)m * 256 + n] = acc[mi][ni][j] + bb;
            }
        }
}

// ---------------------------------------------------------------------------
// K2: fp16 MFMA flash attention — R12 structure (known 77us) + T5 setprio.
// 16 q-rows/wave, 4 waves/block, LDS 52KB, 1024 blocks heavy-first,
// hb pinned per XCD, counted vmcnt (barrier1 waits own VT vmcnt(4)).
// s_setprio(1) wraps QK and PV MFMA clusters: 3 blocks/CU at different qst
// give phase diversity (attn-case T5, m191), unlike lockstep GEMM.
// ---------------------------------------------------------------------------
__global__ __launch_bounds__(256, 3) void flash_mfma(
    const ushort* __restrict__ qf, const ushort* __restrict__ kf,
    const ushort* __restrict__ vt, ushort* __restrict__ ocf)
{
    __shared__ __align__(16) ushort Ks[2][32 * 256];
    __shared__ __align__(16) ushort VTs[256 * 32];
    __shared__ __align__(16) ushort Pls[4][512];

    const int bid = blockIdx.x;
    const int idx = bid >> 3;
    const int hb  = (bid & 7) * 8 + (idx & 7);   // same-XCD hb groups
    const int qst = 15 - (idx >> 3);             // heavy-first
    const int h = hb >> 3, b = hb & 7;

    const int tid = threadIdx.x;
    const int w = tid >> 6, l = tid & 63;
    const int g = l >> 4, c16 = l & 15;
    const size_t qk_base = (size_t)h * QE + (size_t)b * (SEQ * EMBED);
    const size_t vt_base = (size_t)h * QE + (size_t)b * SEQ;

    const int psw = (c16 >> 1) & 3;
    const int rsw = c16 & 7;
    const int qw0 = qst * 64 + w * 16;
    const int q0 = qw0 + c16;

    half8 qfr[8];
    {
        const ushort* qr = qf + qk_base + (size_t)q0 * EMBED + g * 8;
#pragma unroll
        for (int kc = 0; kc < 8; ++kc)
            qfr[kc] = *(const half8*)(qr + kc * 32);
    }

    const ushort* kbase = kf + qk_base;
    const ushort* vbase = vt + vt_base;
    const int krow_l = l >> 5, kblk = l & 31;
    const int vd_l = l >> 2,  vblk = l & 3;
    uint koff[4], voff[4];
#pragma unroll
    for (int j = 0; j < 4; ++j) {
        const int row = 8 * w + 2 * j + krow_l;
        koff[j] = (uint)(row * EMBED + ((kblk ^ (row & 7)) * 8));
        const int d = w * 64 + j * 16 + vd_l;
        const int phi = ((d >> 1) ^ (d >> 3)) & 3;
        voff[j] = (uint)(d * NROWS + ((vblk ^ phi) * 8));
    }

    f32x4 acc[16];
#pragma unroll
    for (int dt = 0; dt < 16; ++dt) acc[dt] = (f32x4){0.f, 0.f, 0.f, 0.f};
    float m_r = -1e30f, l_p = 0.f;

    char* pw = (char*)&Pls[w][0];
    const int nkt = 2 * qst + 2;

    // prologue: stage K[0]
#pragma unroll
    for (int j = 0; j < 4; ++j)
        __builtin_amdgcn_global_load_lds(kbase + koff[j], &Ks[0][(8 * w + 2 * j) * 256], 16, 0, 0);
    asm volatile("s_waitcnt vmcnt(0)" ::: "memory");
    __builtin_amdgcn_s_barrier();
    __builtin_amdgcn_sched_barrier(0);

    for (int kt = 0; kt < nkt; ++kt) {
        // issue VT[kt] FIRST (oldest in queue -> covered by vmcnt(4)),
        // then K[kt+1] (covered by barrier2's vmcnt(0)).
#pragma unroll
        for (int j = 0; j < 4; ++j)
            __builtin_amdgcn_global_load_lds(vbase + voff[j] + kt * 32,
                                             &VTs[(w * 64 + j * 16) * 32], 16, 0, 0);
        const bool havek = (kt + 1 < nkt);
        if (havek) {
            const ushort* kb = kbase + (size_t)(kt + 1) * (32 * EMBED);
#pragma unroll
            for (int j = 0; j < 4; ++j)
                __builtin_amdgcn_global_load_lds(kb + koff[j],
                                                 &Ks[(kt + 1) & 1][(8 * w + 2 * j) * 256], 16, 0, 0);
        }

        const bool active = (kt * 32 <= qw0 + 15);
        if (active) {
            // ---- QK^T on K[kt] (already complete from previous barrier2) ----
            const ushort* Kb = &Ks[kt & 1][0];
            f32x4 s0 = (f32x4){0.f, 0.f, 0.f, 0.f};
            f32x4 s1 = (f32x4){0.f, 0.f, 0.f, 0.f};
            __builtin_amdgcn_s_setprio(1);
#pragma unroll
            for (int kc = 0; kc < 8; ++kc) {
                const int blk = ((kc * 4 + g) ^ rsw) * 8;
                const half8 a0 = *(const half8*)&Kb[c16 * 256 + blk];
                const half8 a1 = *(const half8*)&Kb[(c16 + 16) * 256 + blk];
                s0 = __builtin_amdgcn_mfma_f32_16x16x32_f16(a0, qfr[kc], s0, 0, 0, 0);
                s1 = __builtin_amdgcn_mfma_f32_16x16x32_f16(a1, qfr[kc], s1, 0, 0, 0);
            }
            __builtin_amdgcn_s_setprio(0);
            const int k0b = kt * 32 + 4 * g;
            float p0[4], p1[4];
            float pm = -1e30f;
#pragma unroll
            for (int r = 0; r < 4; ++r) {
                p0[r] = (k0b + r      > q0) ? -1e30f : s0[r];
                p1[r] = (k0b + 16 + r > q0) ? -1e30f : s1[r];
                pm = fmaxf(pm, fmaxf(p0[r], p1[r]));
            }
            if (__any(pm > m_r + 8.f)) {
                float gm = fmaxf(pm, __shfl_xor(pm, 16));
                gm = fmaxf(gm, __shfl_xor(gm, 32));
                const float mn = fmaxf(m_r, gm);
                const float sc = __expf(m_r - mn);
                l_p *= sc;
#pragma unroll
                for (int dt = 0; dt < 16; ++dt) acc[dt] *= sc;
                m_r = mn;
            }
#pragma unroll
            for (int r = 0; r < 4; ++r) {
                p0[r] = __expf(p0[r] - m_r);
                p1[r] = __expf(p1[r] - m_r);
                l_p += p0[r] + p1[r];
            }
#pragma unroll
            for (int t = 0; t < 2; ++t)
#pragma unroll
                for (int u = 0; u < 2; ++u) {
                    const int kk = 16 * t + 4 * g + 2 * u;
                    const int off = c16 * 64 + (((kk >> 3) ^ psw) * 16) + (kk & 7) * 2;
                    const float lo = t ? p1[2 * u] : p0[2 * u];
                    const float hi = t ? p1[2 * u + 1] : p0[2 * u + 1];
                    *(uint*)(pw + off) = (uint)f2h(lo) | ((uint)f2h(hi) << 16);
                }
        }

        // barrier1: own VT landed (K[kt+1] stays in flight when havek)
        if (havek) asm volatile("s_waitcnt vmcnt(4)" ::: "memory");
        else       asm volatile("s_waitcnt vmcnt(0)" ::: "memory");
        __builtin_amdgcn_s_barrier();
        __builtin_amdgcn_sched_barrier(0);

        if (active) {
            const half8 pfrag = *(const half8*)(pw + c16 * 64 + ((g ^ psw) * 16));
            __builtin_amdgcn_s_setprio(1);
#pragma unroll
            for (int dt = 0; dt < 16; ++dt) {
                const int d = dt * 16 + c16;
                const int phi = ((d >> 1) ^ (d >> 3)) & 3;
                const half8 va = *(const half8*)&VTs[d * 32 + ((g ^ phi) * 8)];
                acc[dt] = __builtin_amdgcn_mfma_f32_16x16x32_f16(va, pfrag, acc[dt], 0, 0, 0);
            }
            __builtin_amdgcn_s_setprio(0);
        }

        // barrier2: own K[kt+1] landed; VT buffer free for next iter
        asm volatile("s_waitcnt vmcnt(0)" ::: "memory");
        __builtin_amdgcn_s_barrier();
        __builtin_amdgcn_sched_barrier(0);
    }

    l_p += __shfl_xor(l_p, 16);
    l_p += __shfl_xor(l_p, 32);
    const float inv = 1.f / l_p;
    ushort* orow = ocf + ((size_t)(b * SEQ) + q0) * (HEADS * EMBED) + h * EMBED;
#pragma unroll
    for (int dt = 0; dt < 16; ++dt) {
        const f32x4 o = acc[dt] * inv;
        uint2 P2;
        P2.x = (uint)f2h(o[0]) | ((uint)f2h(o[1]) << 16);
        P2.y = (uint)f2h(o[2]) | ((uint)f2h(o[3]) << 16);
        *(uint2*)(orow + dt * 16 + 4 * g) = P2;
    }
}

extern "C" void kernel_launch(void* const* d_in, const int* in_sizes, int n_in,
                              void* d_out, int out_size, void* d_ws, size_t ws_size,
                              hipStream_t stream) {
    const float* X  = (const float*)d_in[0];
    const float* Wq = (const float*)d_in[1];
    const float* Wk = (const float*)d_in[2];
    const float* Wv = (const float*)d_in[3];
    const float* Wo = (const float*)d_in[4];
    const float* bo = (const float*)d_in[5];

    ushort* ws16 = (ushort*)d_ws;
    ushort* qf   = ws16;                     // [8][8192][256] fp16
    ushort* kf   = ws16 +  8 * QE;           // fp16
    ushort* vtb  = ws16 + 16 * QE;           // [8][256][8192] fp16
    ushort* ocf  = ws16 + 24 * QE;           // [8192][2048] fp16
    ushort* ex   = ws16 + 32 * QE;
    ushort* Xf   = ex;                       // 2M fp16
    ushort* Wqkf = ex + 2097152;             // [4096][256] fp16
    ushort* Wvf  = ex + 2097152 + 1048576;   // [2048][256] fp16
    ushort* Wof  = ex + 2097152 + 1048576 + 524288;   // [256][2048] fp16
    float*  out  = (float*)d_out;

    convert_f16<<<4096, 256, 0, stream>>>(X, Wq, Wk, Wv, Wo, Xf, Wqkf, Wvf, Wof);

    gemm_qkvt<<<3072, 256, 0, stream>>>(Xf, Wqkf, Wvf, qf, kf, vtb);

    flash_mfma<<<1024, 256, 0, stream>>>(qf, kf, vtb, ocf);

    gemm_out_f16<<<512, 256, 0, stream>>>(ocf, Wof, bo, out);
}